// Round 6
// baseline (2369.500 us; speedup 1.0000x reference)
//
#include <hip/hip_runtime.h>
#include <type_traits>

// Precoding GNN: 5 layers of z = Ws*x + Wm*(sum_k x) + Wk*(sum_m x), ReLU(1-4),
// then Frobenius power normalization per batch item.
// M=64 antennas, K=32 users, D=32 hidden, BS=1024.
//
// One 1024-thread block per batch item. Thread t owns nodes t and t+1024
// (node n = m*32+k), all features in registers, fp32 end-to-end.
//
// R1-R5 lesson chain: the per-thread float[32]/vf32 state was NEVER promoted
// to registers. Root cause: clang lowers vec[i] with a RUNTIME index to a
// variable-index GEP on an alloca; SROA cannot slice variable GEPs, so the
// alloca stays in scratch (VGPR_Count pinned at 64, GBs of HBM scratch
// traffic, in every round). Occupancy hints were red herrings.
// Fix: static_for with std::integral_constant indices -> every vector
// subscript is a compile-time constant at the AST level -> clang emits
// insert/extractelement directly -> true SSA registers.

namespace {

constexpr int NTHREADS = 1024;
constexpr int LD = 33;   // LDS row stride for small matrices (conflict-free patterns)

typedef float vf32 __attribute__((ext_vector_type(32)));
typedef float vf8  __attribute__((ext_vector_type(8)));

template <int N, int I = 0, class F>
__device__ __forceinline__ void static_for(F&& f) {
    if constexpr (I < N) {
        f(std::integral_constant<int, I>{});
        static_for<N, I + 1>(f);
    }
}

template <int DIN, int DOUT, bool RELU>
__device__ __forceinline__ void gnn_layer_dev(
    vf32& x1, vf32& x2,
    const float* __restrict__ Wsg, const float* __restrict__ Wmg,
    const float* __restrict__ Wkg,
    float* __restrict__ Wm_l,   // [32*LD]
    float* __restrict__ Wk_l,   // [32*LD]
    float* __restrict__ Abuf,   // [64*LD]
    float* __restrict__ Bbuf,   // [32*LD]
    float* __restrict__ msgk,   // [32*LD]
    int t, int k, int m1, int m2, int lane)
{
    constexpr int CW = (DIN < 8) ? DIN : 8;   // butterfly chunk width

    // ---- phase 0: stage Wm/Wk to LDS (per-lane-row reads later), zero msgk ----
    for (int i = t; i < DOUT * DIN; i += NTHREADS) {
        const int h = i / DIN, d = i % DIN;
        Wm_l[h * LD + d] = Wmg[i];
        Wk_l[h * LD + d] = Wkg[i];
    }
    for (int i = t; i < 32 * LD; i += NTHREADS) msgk[i] = 0.0f;
    __syncthreads();

    // ---- phase 1a: msg_k pair-reduce + LDS atomics ----
    // Thread covers antennas {m1, m2}; lane^32 covers {m1^1, m2^1}; 16 waves
    // cover all 64 antennas via ds_add on msgk[k][d] (32 distinct addresses
    // per half-wave -> conflict-free).
    static_for<DIN>([&](auto D) {
        constexpr int d = decltype(D)::value;
        float s = x1[d] + x2[d];
        s += __shfl_xor(s, 32);
        if (lane < 32) atomicAdd(&msgk[k * LD + d], s);
    });

    // ---- phase 1b: msg_m butterfly (8-feature chunks), fused A[m][k] dot ----
    // The 32 threads sharing antenna m are one contiguous half-wave; masks
    // 1..16 reduce across them. Lane k computes A[m][k] = Wm[k,:].msg_m.
    auto do_msgm = [&](const vf32& x, int m) {
        float acc = 0.0f;
        static_for<(DIN + CW - 1) / CW>([&](auto C) {
            constexpr int c0 = decltype(C)::value * CW;
            vf8 mm;
            static_for<CW>([&](auto J) {
                constexpr int j = decltype(J)::value;
                mm[j] = x[c0 + j];
            });
#pragma unroll
            for (int mask = 1; mask <= 16; mask <<= 1) {
                static_for<CW>([&](auto J) {
                    constexpr int j = decltype(J)::value;
                    mm[j] += __shfl_xor(mm[j], mask);
                });
            }
            if (k < DOUT) {
                static_for<CW>([&](auto J) {
                    constexpr int j = decltype(J)::value;
                    acc += Wm_l[k * LD + c0 + j] * mm[j];
                });
            }
        });
        if (k < DOUT) Abuf[m * LD + k] = acc;
    };
    do_msgm(x1, m1);
    do_msgm(x2, m2);
    __syncthreads();

    // ---- phase 2: B[k][h] = Wk[h,:].msg_k (one dot per thread, LDS only) ----
    if (t < 32 * DOUT) {
        const int kk = t / DOUT, hh = t % DOUT;
        float acc = 0.0f;
        for (int d = 0; d < DIN; ++d) acc += Wk_l[hh * LD + d] * msgk[kk * LD + d];
        Bbuf[kk * LD + hh] = acc;
    }
    __syncthreads();

    // ---- phase 3: z = Ws*x + A[m] + B[k] per node. Ws read from global with
    //      uniform constant offsets -> s_load into SGPRs (proven: SGPR=112).
    //      A read is half-wave-uniform (broadcast); B read conflict-free.
    auto do_node = [&](vf32& x, int m) {
        vf32 acc;
        static_for<DOUT>([&](auto H) {
            constexpr int h = decltype(H)::value;
            acc[h] = Abuf[m * LD + h] + Bbuf[k * LD + h];
        });
        static_for<DIN>([&](auto D) {
            constexpr int d = decltype(D)::value;
            const float xd = x[d];
            static_for<DOUT>([&](auto H) {
                constexpr int h = decltype(H)::value;
                acc[h] += Wsg[h * DIN + d] * xd;
            });
        });
        static_for<DOUT>([&](auto H) {
            constexpr int h = decltype(H)::value;
            x[h] = RELU ? fmaxf(acc[h], 0.0f) : acc[h];
        });
    };
    do_node(x1, m1);
    do_node(x2, m2);
    __syncthreads();  // protect Wm/Wk/msgk/Abuf/Bbuf before next layer restages
}

__global__ void __launch_bounds__(NTHREADS)
__attribute__((amdgpu_waves_per_eu(4, 4)))
gnn_fused(
    const float* __restrict__ xg,
    const float* __restrict__ w1s, const float* __restrict__ w1m, const float* __restrict__ w1k,
    const float* __restrict__ w2s, const float* __restrict__ w2m, const float* __restrict__ w2k,
    const float* __restrict__ w3s, const float* __restrict__ w3m, const float* __restrict__ w3k,
    const float* __restrict__ w4s, const float* __restrict__ w4m, const float* __restrict__ w4k,
    const float* __restrict__ w5s, const float* __restrict__ w5m, const float* __restrict__ w5k,
    float* __restrict__ out)
{
    __shared__ float Wm_l[32 * LD];
    __shared__ float Wk_l[32 * LD];
    __shared__ float Abuf[64 * LD];
    __shared__ float Bbuf[32 * LD];
    __shared__ float msgk[32 * LD];
    __shared__ float red[17];

    const int t = threadIdx.x;
    const int b = blockIdx.x;
    const int k = t & 31;
    const int m1 = t >> 5;
    const int m2 = m1 + 32;
    const int lane = t & 63;
    const int wave = t >> 6;

    vf32 x1, x2;

    // input: (b, 64, 32, 2) -> node n covers floats [2n, 2n+1]
    const float2 a1 = *reinterpret_cast<const float2*>(xg + (size_t)b * 4096 + 2 * t);
    const float2 a2 = *reinterpret_cast<const float2*>(xg + (size_t)b * 4096 + 2048 + 2 * t);
    x1[0] = a1.x; x1[1] = a1.y;
    x2[0] = a2.x; x2[1] = a2.y;

    gnn_layer_dev<2, 32, true>(x1, x2, w1s, w1m, w1k,
                               Wm_l, Wk_l, Abuf, Bbuf, msgk, t, k, m1, m2, lane);
    gnn_layer_dev<32, 32, true>(x1, x2, w2s, w2m, w2k,
                                Wm_l, Wk_l, Abuf, Bbuf, msgk, t, k, m1, m2, lane);
    gnn_layer_dev<32, 32, true>(x1, x2, w3s, w3m, w3k,
                                Wm_l, Wk_l, Abuf, Bbuf, msgk, t, k, m1, m2, lane);
    gnn_layer_dev<32, 32, true>(x1, x2, w4s, w4m, w4k,
                                Wm_l, Wk_l, Abuf, Bbuf, msgk, t, k, m1, m2, lane);
    gnn_layer_dev<32, 2, false>(x1, x2, w5s, w5m, w5k,
                                Wm_l, Wk_l, Abuf, Bbuf, msgk, t, k, m1, m2, lane);

    // ---- pwr_norm: alpha = rsqrt(sum over all (m,k,c) of z^2) ----
    float p = x1[0] * x1[0] + x1[1] * x1[1] + x2[0] * x2[0] + x2[1] * x2[1];
#pragma unroll
    for (int mask = 1; mask <= 32; mask <<= 1) p += __shfl_xor(p, mask);
    if (lane == 0) red[wave] = p;
    __syncthreads();
    if (t == 0) {
        float tot = 0.0f;
#pragma unroll
        for (int i = 0; i < 16; ++i) tot += red[i];
        red[16] = rsqrtf(tot);
    }
    __syncthreads();
    const float alpha = red[16];

    float2 o1, o2;
    o1.x = alpha * x1[0]; o1.y = alpha * x1[1];
    o2.x = alpha * x2[0]; o2.y = alpha * x2[1];
    *reinterpret_cast<float2*>(out + (size_t)b * 4096 + 2 * t) = o1;
    *reinterpret_cast<float2*>(out + (size_t)b * 4096 + 2048 + 2 * t) = o2;
}

}  // namespace

extern "C" void kernel_launch(void* const* d_in, const int* in_sizes, int n_in,
                              void* d_out, int out_size, void* d_ws, size_t ws_size,
                              hipStream_t stream) {
    const float* xg  = (const float*)d_in[0];
    const float* w1s = (const float*)d_in[1];
    const float* w1m = (const float*)d_in[2];
    const float* w1k = (const float*)d_in[3];
    const float* w2s = (const float*)d_in[4];
    const float* w2m = (const float*)d_in[5];
    const float* w2k = (const float*)d_in[6];
    const float* w3s = (const float*)d_in[7];
    const float* w3m = (const float*)d_in[8];
    const float* w3k = (const float*)d_in[9];
    const float* w4s = (const float*)d_in[10];
    const float* w4m = (const float*)d_in[11];
    const float* w4k = (const float*)d_in[12];
    const float* w5s = (const float*)d_in[13];
    const float* w5m = (const float*)d_in[14];
    const float* w5k = (const float*)d_in[15];
    float* out = (float*)d_out;

    hipLaunchKernelGGL(gnn_fused, dim3(1024), dim3(NTHREADS), 0, stream,
                       xg, w1s, w1m, w1k, w2s, w2m, w2k, w3s, w3m, w3k,
                       w4s, w4m, w4k, w5s, w5m, w5k, out);
}

// Round 8
// 1516.312 us; speedup vs baseline: 1.5627x; 1.5627x over previous
//
#include <hip/hip_runtime.h>
#include <hip/hip_fp16.h>

// Precoding GNN: 5 layers of z = Ws*x + Wm*(sum_k x) + Wk*(sum_m x), ReLU(1-4),
// then Frobenius power normalization per batch item.
// M=64 antennas, K=32 users, D=32 hidden, BS=1024.
//
// One 1024-thread block per batch item; thread t owns nodes t and t+1024.
//
// R1-R6: persistent per-thread state (64 floats) never got into registers
// (VGPR pinned at 64, GBs of scratch). Design needs <64 VGPRs BY CONSTRUCTION:
//   - ALL node state in LDS as packed fp16 Xp[featpair][node] (128 KiB,
//     thread-private columns -> conflict-free).
//   - Registers hold only transient named scalars (macro-unrolled).
//   - Weights via wave-uniform global loads -> SGPRs.
// R7: NaN. Activation std grows ~28x/layer (64-antenna aggregation through
// Glorot rows, no bias): L4 std ~8e4 > fp16 max 65504 -> inf. FIX: the net
// is bias-free linear + ReLU => positively homogeneous, f(c*x)=c*f(x), and
// pwr_norm is scale-invariant. Scale input by 2^-6 (exact): L4 std ~1.2e3,
// in-range; final output unchanged.

namespace {

constexpr int NTHREADS = 1024;
constexpr float INPUT_SCALE = 0.015625f;   // 2^-6, exact; output is scale-invariant

#define RPT8(X) X(0)X(1)X(2)X(3)X(4)X(5)X(6)X(7)
#define RPT32(X) X(0)X(1)X(2)X(3)X(4)X(5)X(6)X(7)X(8)X(9)X(10)X(11)X(12)X(13)X(14)X(15) \
                 X(16)X(17)X(18)X(19)X(20)X(21)X(22)X(23)X(24)X(25)X(26)X(27)X(28)X(29)X(30)X(31)
#define RPT16P(X) X(0,0,1)X(1,2,3)X(2,4,5)X(3,6,7)X(4,8,9)X(5,10,11)X(6,12,13)X(7,14,15) \
                  X(8,16,17)X(9,18,19)X(10,20,21)X(11,22,23)X(12,24,25)X(13,26,27)X(14,28,29)X(15,30,31)

__device__ __forceinline__ unsigned pk(float a, float b) {
    __half2 h = __floats2half2_rn(a, b);
    return *reinterpret_cast<unsigned*>(&h);
}
__device__ __forceinline__ float2 upk(unsigned w) {
    __half2 h;
    *reinterpret_cast<unsigned*>(&h) = w;
    return __half22float2(h);
}

// ---------------- layer 1: d_in = 2 (input in registers), d_out = 32 ----------------
__device__ __forceinline__ void layer_in(
    const float* __restrict__ Wsg, const float* __restrict__ Wmg, const float* __restrict__ Wkg,
    float2 a1, float2 a2,
    unsigned* __restrict__ Xp, float* __restrict__ Wm_l, float* __restrict__ Wk_l,
    float* __restrict__ Abuf, float* __restrict__ Bbuf, float* __restrict__ msgk,
    int t, int k, int m1, int m2, int lane)
{
    if (t < 64) {   // stage 32x2 weights
        const int h = t >> 1, d = t & 1;
        Wm_l[h * 33 + d] = Wmg[t];
        Wk_l[h * 33 + d] = Wkg[t];
    }
    for (int i = t; i < 32 * 33; i += NTHREADS) msgk[i] = 0.0f;
    __syncthreads();

    // msg_k
    float s0 = a1.x + a2.x, s1 = a1.y + a2.y;
    s0 += __shfl_xor(s0, 32);
    s1 += __shfl_xor(s1, 32);
    if (lane < 32) {
        atomicAdd(&msgk[k * 33 + 0], s0);
        atomicAdd(&msgk[k * 33 + 1], s1);
    }
    // msg_m butterflies
    float f0 = a1.x, f1 = a1.y, g0 = a2.x, g1 = a2.y;
#pragma unroll
    for (int mask = 1; mask <= 16; mask <<= 1) {
        f0 += __shfl_xor(f0, mask); f1 += __shfl_xor(f1, mask);
        g0 += __shfl_xor(g0, mask); g1 += __shfl_xor(g1, mask);
    }
    Abuf[m1 * 33 + k] = Wm_l[k * 33 + 0] * f0 + Wm_l[k * 33 + 1] * f1;
    Abuf[m2 * 33 + k] = Wm_l[k * 33 + 0] * g0 + Wm_l[k * 33 + 1] * g1;
    __syncthreads();

    // B[k][h] = Wk[h,:].msg_k
    {
        const int kk = t >> 5, hh = t & 31;
        Bbuf[kk * 33 + hh] = Wk_l[hh * 33 + 0] * msgk[kk * 33 + 0]
                           + Wk_l[hh * 33 + 1] * msgk[kk * 33 + 1];
    }
    __syncthreads();

    // z = Ws*x + A + B, relu, -> Xp (fp16)
#pragma unroll 1
    for (int half = 0; half < 2; ++half) {
        const int n = half ? (t + 1024) : t;
        const int m = half ? m2 : m1;
        const float xa = half ? a2.x : a1.x;
        const float xb = half ? a2.y : a1.y;
        const int ab = m * 33, bb = k * 33;
#define DECL_ACC(h) float acc##h = Abuf[ab + h] + Bbuf[bb + h] + Wsg[h * 2] * xa + Wsg[h * 2 + 1] * xb;
        RPT32(DECL_ACC)
#undef DECL_ACC
#define ST(p, h0, h1) Xp[p * 2048 + n] = pk(fmaxf(acc##h0, 0.0f), fmaxf(acc##h1, 0.0f));
        RPT16P(ST)
#undef ST
    }
    __syncthreads();
}

// ---------------- layers 2-4: 32 -> 32, relu ----------------
__device__ __forceinline__ void layer_mid(
    const float* __restrict__ Wsg, const float* __restrict__ Wmg, const float* __restrict__ Wkg,
    unsigned* __restrict__ Xp, float* __restrict__ Wm_l, float* __restrict__ Wk_l,
    float* __restrict__ Abuf, float* __restrict__ Bbuf, float* __restrict__ msgk,
    int t, int k, int m1, int m2, int lane)
{
    {   // stage 32x32 weights: exactly one element per thread
        const int h = t >> 5, d = t & 31;
        Wm_l[h * 33 + d] = Wmg[t];
        Wk_l[h * 33 + d] = Wkg[t];
    }
    for (int i = t; i < 32 * 33; i += NTHREADS) msgk[i] = 0.0f;
    __syncthreads();

    // ---- phase 1: msg_k atomics + msg_m butterflies, chunked 8 feats ----
    const int n1 = t, n2 = t + 1024;
    const int wmrow = k * 33;
    float accA1 = 0.0f, accA2 = 0.0f;
#pragma unroll 1
    for (int c = 0; c < 4; ++c) {
        const int base = (c * 4) * 2048;
        float f0, f1, f2, f3, f4, f5, f6, f7, g0, g1, g2, g3, g4, g5, g6, g7;
        {
            float2 u;
            u = upk(Xp[base + n1]);        f0 = u.x; f1 = u.y;
            u = upk(Xp[base + 2048 + n1]); f2 = u.x; f3 = u.y;
            u = upk(Xp[base + 4096 + n1]); f4 = u.x; f5 = u.y;
            u = upk(Xp[base + 6144 + n1]); f6 = u.x; f7 = u.y;
            u = upk(Xp[base + n2]);        g0 = u.x; g1 = u.y;
            u = upk(Xp[base + 2048 + n2]); g2 = u.x; g3 = u.y;
            u = upk(Xp[base + 4096 + n2]); g4 = u.x; g5 = u.y;
            u = upk(Xp[base + 6144 + n2]); g6 = u.x; g7 = u.y;
        }
        // msg_k partials (pair + xor32 + 16-wave atomic)
#define MK(j) { float s = f##j + g##j; s += __shfl_xor(s, 32); \
                if (lane < 32) atomicAdd(&msgk[wmrow + c * 8 + j], s); }
        RPT8(MK)
#undef MK
        // butterfly node 1 over its 32-lane antenna group, dot with Wm row k
#pragma unroll
        for (int mask = 1; mask <= 16; mask <<= 1) {
#define BF(j) f##j += __shfl_xor(f##j, mask);
            RPT8(BF)
#undef BF
        }
#define AC1(j) accA1 += Wm_l[wmrow + c * 8 + j] * f##j;
        RPT8(AC1)
#undef AC1
        // butterfly node 2
#pragma unroll
        for (int mask = 1; mask <= 16; mask <<= 1) {
#define BF(j) g##j += __shfl_xor(g##j, mask);
            RPT8(BF)
#undef BF
        }
#define AC2(j) accA2 += Wm_l[wmrow + c * 8 + j] * g##j;
        RPT8(AC2)
#undef AC2
    }
    Abuf[m1 * 33 + k] = accA1;
    Abuf[m2 * 33 + k] = accA2;
    __syncthreads();

    // ---- phase 2: B[k][h] = Wk[h,:].msg_k ----
    {
        const int kk = t >> 5, hh = t & 31;
        float acc = 0.0f;
#pragma unroll
        for (int d = 0; d < 32; ++d) acc += Wk_l[hh * 33 + d] * msgk[kk * 33 + d];
        Bbuf[kk * 33 + hh] = acc;
    }
    __syncthreads();

    // ---- phase 3: z = Ws*x + A[m] + B[k], relu, in-place (own column) ----
#pragma unroll 1
    for (int half = 0; half < 2; ++half) {
        const int n = half ? n2 : n1;
        const int m = half ? m2 : m1;
        const int ab = m * 33, bb = k * 33;
#define DECL_ACC(h) float acc##h = Abuf[ab + h] + Bbuf[bb + h];
        RPT32(DECL_ACC)
#undef DECL_ACC
#pragma unroll 4
        for (int p = 0; p < 16; ++p) {
            const float2 xd = upk(Xp[p * 2048 + n]);
            const float* wc = Wsg + 2 * p;   // Ws[h][2p], Ws[h][2p+1] at wc[h*32], wc[h*32+1]
#define FMA_H(h) acc##h += wc[h * 32] * xd.x + wc[h * 32 + 1] * xd.y;
            RPT32(FMA_H)
#undef FMA_H
        }
#define ST(p, h0, h1) Xp[p * 2048 + n] = pk(fmaxf(acc##h0, 0.0f), fmaxf(acc##h1, 0.0f));
        RPT16P(ST)
#undef ST
    }
    __syncthreads();
}

// ---------------- layer 5: 32 -> 2, no relu, outputs to registers ----------------
__device__ __forceinline__ void layer_out(
    const float* __restrict__ Wsg, const float* __restrict__ Wmg, const float* __restrict__ Wkg,
    unsigned* __restrict__ Xp, float* __restrict__ Wm_l, float* __restrict__ Wk_l,
    float* __restrict__ Abuf, float* __restrict__ Bbuf, float* __restrict__ msgk,
    float2& o1, float2& o2,
    int t, int k, int m1, int m2, int lane)
{
    if (t < 64) {   // stage 2x32 weights
        const int h = t >> 5, d = t & 31;
        Wm_l[h * 33 + d] = Wmg[t];
        Wk_l[h * 33 + d] = Wkg[t];
    }
    for (int i = t; i < 32 * 33; i += NTHREADS) msgk[i] = 0.0f;
    __syncthreads();

    const int n1 = t, n2 = t + 1024;
    float accA1 = 0.0f, accA2 = 0.0f;
#pragma unroll 1
    for (int c = 0; c < 4; ++c) {
        const int base = (c * 4) * 2048;
        float f0, f1, f2, f3, f4, f5, f6, f7, g0, g1, g2, g3, g4, g5, g6, g7;
        {
            float2 u;
            u = upk(Xp[base + n1]);        f0 = u.x; f1 = u.y;
            u = upk(Xp[base + 2048 + n1]); f2 = u.x; f3 = u.y;
            u = upk(Xp[base + 4096 + n1]); f4 = u.x; f5 = u.y;
            u = upk(Xp[base + 6144 + n1]); f6 = u.x; f7 = u.y;
            u = upk(Xp[base + n2]);        g0 = u.x; g1 = u.y;
            u = upk(Xp[base + 2048 + n2]); g2 = u.x; g3 = u.y;
            u = upk(Xp[base + 4096 + n2]); g4 = u.x; g5 = u.y;
            u = upk(Xp[base + 6144 + n2]); g6 = u.x; g7 = u.y;
        }
#define MK(j) { float s = f##j + g##j; s += __shfl_xor(s, 32); \
                if (lane < 32) atomicAdd(&msgk[k * 33 + c * 8 + j], s); }
        RPT8(MK)
#undef MK
#pragma unroll
        for (int mask = 1; mask <= 16; mask <<= 1) {
#define BF(j) f##j += __shfl_xor(f##j, mask);
            RPT8(BF)
#undef BF
        }
        if (k < 2) {
#define AC1(j) accA1 += Wm_l[k * 33 + c * 8 + j] * f##j;
            RPT8(AC1)
#undef AC1
        }
#pragma unroll
        for (int mask = 1; mask <= 16; mask <<= 1) {
#define BF(j) g##j += __shfl_xor(g##j, mask);
            RPT8(BF)
#undef BF
        }
        if (k < 2) {
#define AC2(j) accA2 += Wm_l[k * 33 + c * 8 + j] * g##j;
            RPT8(AC2)
#undef AC2
        }
    }
    if (k < 2) {
        Abuf[m1 * 33 + k] = accA1;
        Abuf[m2 * 33 + k] = accA2;
    }
    __syncthreads();

    if (t < 64) {   // B[k][h], h<2
        const int kk = t >> 1, hh = t & 1;
        float acc = 0.0f;
#pragma unroll
        for (int d = 0; d < 32; ++d) acc += Wk_l[hh * 33 + d] * msgk[kk * 33 + d];
        Bbuf[kk * 33 + hh] = acc;
    }
    __syncthreads();

#pragma unroll 1
    for (int half = 0; half < 2; ++half) {
        const int n = half ? n2 : n1;
        const int m = half ? m2 : m1;
        float acc0 = Abuf[m * 33 + 0] + Bbuf[k * 33 + 0];
        float acc1 = Abuf[m * 33 + 1] + Bbuf[k * 33 + 1];
#pragma unroll 4
        for (int p = 0; p < 16; ++p) {
            const float2 xd = upk(Xp[p * 2048 + n]);
            const float* wc = Wsg + 2 * p;
            acc0 += wc[0] * xd.x + wc[1] * xd.y;
            acc1 += wc[32] * xd.x + wc[33] * xd.y;
        }
        if (half) { o2.x = acc0; o2.y = acc1; }
        else      { o1.x = acc0; o1.y = acc1; }
    }
}

__global__ void __launch_bounds__(NTHREADS) gnn_fused(
    const float* __restrict__ xg,
    const float* __restrict__ w1s, const float* __restrict__ w1m, const float* __restrict__ w1k,
    const float* __restrict__ w2s, const float* __restrict__ w2m, const float* __restrict__ w2k,
    const float* __restrict__ w3s, const float* __restrict__ w3m, const float* __restrict__ w3k,
    const float* __restrict__ w4s, const float* __restrict__ w4m, const float* __restrict__ w4k,
    const float* __restrict__ w5s, const float* __restrict__ w5m, const float* __restrict__ w5k,
    float* __restrict__ out)
{
    __shared__ unsigned Xp[16 * 2048];   // fp16x2-packed state, 128 KiB, column = node
    __shared__ float Wm_l[32 * 33];
    __shared__ float Wk_l[32 * 33];
    __shared__ float Abuf[64 * 33];
    __shared__ float Bbuf[32 * 33];
    __shared__ float msgk[32 * 33];
    __shared__ float red[17];

    const int t = threadIdx.x;
    const int b = blockIdx.x;
    const int k = t & 31;
    const int m1 = t >> 5;
    const int m2 = m1 + 32;
    const int lane = t & 63;
    const int wave = t >> 6;

    // input: (b, 64, 32, 2) -> node n covers floats [2n, 2n+1].
    // Scale by 2^-6 (exact): network is positively homogeneous and the final
    // pwr_norm is scale-invariant; keeps fp16 activations in range.
    float2 a1 = *reinterpret_cast<const float2*>(xg + (size_t)b * 4096 + 2 * t);
    float2 a2 = *reinterpret_cast<const float2*>(xg + (size_t)b * 4096 + 2048 + 2 * t);
    a1.x *= INPUT_SCALE; a1.y *= INPUT_SCALE;
    a2.x *= INPUT_SCALE; a2.y *= INPUT_SCALE;

    layer_in (w1s, w1m, w1k, a1, a2, Xp, Wm_l, Wk_l, Abuf, Bbuf, msgk, t, k, m1, m2, lane);
    layer_mid(w2s, w2m, w2k, Xp, Wm_l, Wk_l, Abuf, Bbuf, msgk, t, k, m1, m2, lane);
    layer_mid(w3s, w3m, w3k, Xp, Wm_l, Wk_l, Abuf, Bbuf, msgk, t, k, m1, m2, lane);
    layer_mid(w4s, w4m, w4k, Xp, Wm_l, Wk_l, Abuf, Bbuf, msgk, t, k, m1, m2, lane);

    float2 o1, o2;
    layer_out(w5s, w5m, w5k, Xp, Wm_l, Wk_l, Abuf, Bbuf, msgk, o1, o2, t, k, m1, m2, lane);

    // ---- pwr_norm: alpha = rsqrt(sum over all (m,k,c) of z^2) ----
    float p = o1.x * o1.x + o1.y * o1.y + o2.x * o2.x + o2.y * o2.y;
#pragma unroll
    for (int mask = 1; mask <= 32; mask <<= 1) p += __shfl_xor(p, mask);
    if (lane == 0) red[wave] = p;
    __syncthreads();
    if (t == 0) {
        float tot = 0.0f;
#pragma unroll
        for (int i = 0; i < 16; ++i) tot += red[i];
        red[16] = rsqrtf(tot);
    }
    __syncthreads();
    const float alpha = red[16];

    float2 r1, r2;
    r1.x = alpha * o1.x; r1.y = alpha * o1.y;
    r2.x = alpha * o2.x; r2.y = alpha * o2.y;
    *reinterpret_cast<float2*>(out + (size_t)b * 4096 + 2 * t) = r1;
    *reinterpret_cast<float2*>(out + (size_t)b * 4096 + 2048 + 2 * t) = r2;
}

}  // namespace

extern "C" void kernel_launch(void* const* d_in, const int* in_sizes, int n_in,
                              void* d_out, int out_size, void* d_ws, size_t ws_size,
                              hipStream_t stream) {
    const float* xg  = (const float*)d_in[0];
    const float* w1s = (const float*)d_in[1];
    const float* w1m = (const float*)d_in[2];
    const float* w1k = (const float*)d_in[3];
    const float* w2s = (const float*)d_in[4];
    const float* w2m = (const float*)d_in[5];
    const float* w2k = (const float*)d_in[6];
    const float* w3s = (const float*)d_in[7];
    const float* w3m = (const float*)d_in[8];
    const float* w3k = (const float*)d_in[9];
    const float* w4s = (const float*)d_in[10];
    const float* w4m = (const float*)d_in[11];
    const float* w4k = (const float*)d_in[12];
    const float* w5s = (const float*)d_in[13];
    const float* w5m = (const float*)d_in[14];
    const float* w5k = (const float*)d_in[15];
    float* out = (float*)d_out;

    hipLaunchKernelGGL(gnn_fused, dim3(1024), dim3(NTHREADS), 0, stream,
                       xg, w1s, w1m, w1k, w2s, w2m, w2k, w3s, w3m, w3k,
                       w4s, w4m, w4k, w5s, w5m, w5k, out);
}

// Round 11
// 236.962 us; speedup vs baseline: 9.9995x; 6.3990x over previous
//
#include <hip/hip_runtime.h>
#include <hip/hip_fp16.h>

// Precoding GNN: 5 layers of z = Ws*x + Wm*(sum_k x) + Wk*(sum_m x), ReLU(1-4),
// then Frobenius power normalization per batch item.
// M=64 antennas, K=32 users, D=32 hidden, BS=1024.
//
// One 1024-thread block per batch item.
//
// R1-R6: per-thread state never promoted to registers (VGPR pinned 64).
// R8: all state in LDS fp16, scalar math -> correct, 1516us.
// R9/R10: MFMA path NaN'd at input scales 2^-8 AND 2^-11: a single global
//   scale must absorb 4 layers of compounded aggregation-gain uncertainty
//   (gain = 64*||W||*align per layer) -- wider than fp16's window once msg
//   (64x acts) must fit too.
// R11: per-layer renormalization. Net is bias-free + positively homogeneous;
//   pwr_norm cancels any per-item scalar => multiply every stored activation
//   by LAYER_SCALE = 2^-7 (compensates the ~64x aggregation gain), input
//   scale 2^-4. Worst-case bound (||W||<=2.3): Y_L <= 1.75*Y_{L-1} =>
//   msg el <= ~77, A/B el <= ~85 << 65504. Overflow impossible at any depth;
//   typical values stay in fp16 normal range. Same multiplier for every
//   item/lane => output unchanged.

namespace {

constexpr int NTHREADS = 1024;
constexpr float INPUT_SCALE = 0.0625f;      // 2^-4 exact
constexpr float LAYER_SCALE = 0.0078125f;   // 2^-7 exact, applied at each act store

typedef _Float16 half8 __attribute__((ext_vector_type(8)));
typedef float    f32x4 __attribute__((ext_vector_type(4)));
typedef unsigned uint4v __attribute__((ext_vector_type(4)));

#define RPT32(X) X(0)X(1)X(2)X(3)X(4)X(5)X(6)X(7)X(8)X(9)X(10)X(11)X(12)X(13)X(14)X(15) \
                 X(16)X(17)X(18)X(19)X(20)X(21)X(22)X(23)X(24)X(25)X(26)X(27)X(28)X(29)X(30)X(31)
#define RPT16P(X) X(0,0,1)X(1,2,3)X(2,4,5)X(3,6,7)X(4,8,9)X(5,10,11)X(6,12,13)X(7,14,15) \
                  X(8,16,17)X(9,18,19)X(10,20,21)X(11,22,23)X(12,24,25)X(13,26,27)X(14,28,29)X(15,30,31)

__device__ __forceinline__ unsigned pk(float a, float b) {
    __half2 h = __floats2half2_rn(a, b);
    return *reinterpret_cast<unsigned*>(&h);
}
__device__ __forceinline__ float2 upk(unsigned w) {
    __half2 h;
    *reinterpret_cast<unsigned*>(&h) = w;
    return __half22float2(h);
}

// MFMA A-frag (8 fp16: row fixed, k = quad*8..quad*8+7) from an
// 18-dword-stride fp16x2 LDS matrix. Layout: A[m=lane&15][k=quad*8+j].
__device__ __forceinline__ half8 load_afrag(const unsigned* base18, int row, int quad) {
    const unsigned* ap = base18 + row * 18 + quad * 4;
    const uint2 p0 = *reinterpret_cast<const uint2*>(ap);
    const uint2 p1 = *reinterpret_cast<const uint2*>(ap + 2);
    uint4v raw;
    raw.x = p0.x; raw.y = p0.y; raw.z = p1.x; raw.w = p1.y;
    return __builtin_bit_cast(half8, raw);
}

// MFMA B-frag for weight W (d_out x 32 fp32, row-major):
// B[k=quad*8+j][n=lane&15] = W[h=n][d=k]  =>  D = A * B = X * W^T.
__device__ __forceinline__ half8 load_wfrag(const float* __restrict__ W, int h, int quad) {
    const float4* wr = reinterpret_cast<const float4*>(W + h * 32 + quad * 8);
    const float4 w0 = wr[0];
    const float4 w1 = wr[1];
    half8 b;
    b[0] = (_Float16)w0.x; b[1] = (_Float16)w0.y; b[2] = (_Float16)w0.z; b[3] = (_Float16)w0.w;
    b[4] = (_Float16)w1.x; b[5] = (_Float16)w1.y; b[6] = (_Float16)w1.z; b[7] = (_Float16)w1.w;
    return b;
}

// ---- phase A: msg_m[64][32] (rows 0-63) and msg_k[32][32] (rows 64-95) ----
// waves 8-15: msg_m (2 items each of 32 reads); waves 0-7: msg_k (64 reads).
__device__ __forceinline__ void phase_msg(const unsigned* __restrict__ Xh,
                                          unsigned* __restrict__ MSG, int t) {
    if (t >= 512) {
#pragma unroll 1
        for (int it = 0; it < 2; ++it) {
            const int item = (t - 512) + it * 512;
            const int m = item >> 4, fp = item & 15;
            float s0 = 0.f, s1 = 0.f;
#pragma unroll 8
            for (int kk = 0; kk < 32; ++kk) {
                const int k = (kk + m) & 31;   // rotate start: spreads banks
                const float2 u = upk(Xh[(m * 32 + k) * 18 + fp]);
                s0 += u.x; s1 += u.y;
            }
            MSG[m * 18 + fp] = pk(s0, s1);
        }
    } else {
        const int k = t >> 4, fp = t & 15;
        float s0 = 0.f, s1 = 0.f;
#pragma unroll 8
        for (int mm = 0; mm < 64; ++mm) {
            const float2 u = upk(Xh[(mm * 32 + k) * 18 + fp]);
            s0 += u.x; s1 += u.y;
        }
        MSG[(64 + k) * 18 + fp] = pk(s0, s1);
    }
}

// ---- phase B: A[64][32] = msg_m*Wm^T (waves 0-7), B[32][32] = msg_k*Wk^T
//      (waves 8-11), 1 MFMA each; D stored fp16 into AB rows 0-63 / 64-95 ----
__device__ __forceinline__ void phase_small(const float* __restrict__ Wmg,
                                            const float* __restrict__ Wkg,
                                            const unsigned* __restrict__ MSG,
                                            unsigned* __restrict__ ABu, int t) {
    const int w = t >> 6, lane = t & 63;
    if (w < 12) {
        const int isb = (w >= 8);
        const int ww = isb ? (w - 8) : w;
        const int mt = ww >> 1, nt = ww & 1;
        const int rowbase = (isb ? 64 : 0) + mt * 16;
        const int quad = lane >> 4, col = lane & 15;
        const half8 a = load_afrag(MSG, rowbase + col, quad);
        const int h = nt * 16 + col;
        const half8 b = load_wfrag(isb ? Wkg : Wmg, h, quad);
        f32x4 c = {0.f, 0.f, 0.f, 0.f};
        c = __builtin_amdgcn_mfma_f32_16x16x32_f16(a, b, c, 0, 0, 0);
        _Float16* ABf = reinterpret_cast<_Float16*>(ABu);
        const int r0 = rowbase + quad * 4;
        ABf[(r0 + 0) * 36 + h] = (_Float16)c[0];
        ABf[(r0 + 1) * 36 + h] = (_Float16)c[1];
        ABf[(r0 + 2) * 36 + h] = (_Float16)c[2];
        ABf[(r0 + 3) * 36 + h] = (_Float16)c[3];
    }
}

// ---- phase C: Z[2048][32] = X*Ws^T + A[m]+B[k] (acc init), relu,
//      scale by LAYER_SCALE, store in place ----
__device__ __forceinline__ void phase_main(const float* __restrict__ Wsg,
                                           unsigned* __restrict__ Xh,
                                           const unsigned* __restrict__ ABu, int t) {
    const int w = t >> 6, lane = t & 63;
    const int quad = lane >> 4, col = lane & 15;
    const half8 b0 = load_wfrag(Wsg, col, quad);        // Ntile 0: h = col
    const half8 b1 = load_wfrag(Wsg, 16 + col, quad);   // Ntile 1: h = col+16
    const _Float16* ABf = reinterpret_cast<const _Float16*>(ABu);
    _Float16* Xf = reinterpret_cast<_Float16*>(Xh);
#pragma unroll 2
    for (int i = 0; i < 8; ++i) {
        const int T = w + i * 16;          // this wave owns rows T*16..T*16+15
        const int node0 = T * 16;
        const int m = T >> 1;              // all 16 rows share antenna m
        const half8 a = load_afrag(Xh, node0 + col, quad);
        const int kr = (T & 1) * 16 + quad * 4;  // user index of rows quad*4..+3
        const int h0 = col, h1 = 16 + col;
        const float am0 = (float)ABf[m * 36 + h0];
        const float am1 = (float)ABf[m * 36 + h1];
        f32x4 c0, c1;
        c0[0] = am0 + (float)ABf[(64 + kr + 0) * 36 + h0];
        c0[1] = am0 + (float)ABf[(64 + kr + 1) * 36 + h0];
        c0[2] = am0 + (float)ABf[(64 + kr + 2) * 36 + h0];
        c0[3] = am0 + (float)ABf[(64 + kr + 3) * 36 + h0];
        c1[0] = am1 + (float)ABf[(64 + kr + 0) * 36 + h1];
        c1[1] = am1 + (float)ABf[(64 + kr + 1) * 36 + h1];
        c1[2] = am1 + (float)ABf[(64 + kr + 2) * 36 + h1];
        c1[3] = am1 + (float)ABf[(64 + kr + 3) * 36 + h1];
        c0 = __builtin_amdgcn_mfma_f32_16x16x32_f16(a, b0, c0, 0, 0, 0);
        c1 = __builtin_amdgcn_mfma_f32_16x16x32_f16(a, b1, c1, 0, 0, 0);
        const int nr = node0 + quad * 4;   // D rows: quad*4 + reg
        Xf[(nr + 0) * 36 + h0] = (_Float16)(fmaxf(c0[0], 0.f) * LAYER_SCALE);
        Xf[(nr + 1) * 36 + h0] = (_Float16)(fmaxf(c0[1], 0.f) * LAYER_SCALE);
        Xf[(nr + 2) * 36 + h0] = (_Float16)(fmaxf(c0[2], 0.f) * LAYER_SCALE);
        Xf[(nr + 3) * 36 + h0] = (_Float16)(fmaxf(c0[3], 0.f) * LAYER_SCALE);
        Xf[(nr + 0) * 36 + h1] = (_Float16)(fmaxf(c1[0], 0.f) * LAYER_SCALE);
        Xf[(nr + 1) * 36 + h1] = (_Float16)(fmaxf(c1[1], 0.f) * LAYER_SCALE);
        Xf[(nr + 2) * 36 + h1] = (_Float16)(fmaxf(c1[2], 0.f) * LAYER_SCALE);
        Xf[(nr + 3) * 36 + h1] = (_Float16)(fmaxf(c1[3], 0.f) * LAYER_SCALE);
    }
}

__global__ void __launch_bounds__(NTHREADS) gnn_fused(
    const float* __restrict__ xg,
    const float* __restrict__ w1s, const float* __restrict__ w1m, const float* __restrict__ w1k,
    const float* __restrict__ w2s, const float* __restrict__ w2m, const float* __restrict__ w2k,
    const float* __restrict__ w3s, const float* __restrict__ w3m, const float* __restrict__ w3k,
    const float* __restrict__ w4s, const float* __restrict__ w4m, const float* __restrict__ w4k,
    const float* __restrict__ w5s, const float* __restrict__ w5m, const float* __restrict__ w5k,
    float* __restrict__ out)
{
    __shared__ __align__(16) unsigned Xh[2048 * 18];   // node state fp16x2, 144 KiB
    __shared__ __align__(16) unsigned MSG[96 * 18];    // msg_m | msg_k, fp16x2
    __shared__ __align__(16) unsigned ABu[96 * 18];    // A | B, fp16 (halves, stride 36)
    __shared__ float red[17];

    const int t = threadIdx.x;
    const int b = blockIdx.x;
    const int k = t & 31;
    const int m1 = t >> 5;
    const int m2 = m1 + 32;
    const int lane = t & 63;
    const int wave = t >> 6;

    float2 a1 = *reinterpret_cast<const float2*>(xg + (size_t)b * 4096 + 2 * t);
    float2 a2 = *reinterpret_cast<const float2*>(xg + (size_t)b * 4096 + 2048 + 2 * t);
    a1.x *= INPUT_SCALE; a1.y *= INPUT_SCALE;
    a2.x *= INPUT_SCALE; a2.y *= INPUT_SCALE;

    _Float16* ABf = reinterpret_cast<_Float16*>(ABu);
    float* MSGf = reinterpret_cast<float*>(MSG);

    // ================= layer 1 (d_in=2, scalar path) =================
    if (t < 64) MSGf[t] = 0.f;
    __syncthreads();
    {
        float s0 = a1.x + a2.x, s1 = a1.y + a2.y;
        s0 += __shfl_xor(s0, 32);
        s1 += __shfl_xor(s1, 32);
        if (lane < 32) {
            atomicAdd(&MSGf[2 * k], s0);
            atomicAdd(&MSGf[2 * k + 1], s1);
        }
        float f0 = a1.x, f1 = a1.y, g0 = a2.x, g1 = a2.y;
#pragma unroll
        for (int mask = 1; mask <= 16; mask <<= 1) {
            f0 += __shfl_xor(f0, mask); f1 += __shfl_xor(f1, mask);
            g0 += __shfl_xor(g0, mask); g1 += __shfl_xor(g1, mask);
        }
        const float2 wm = *reinterpret_cast<const float2*>(w1m + 2 * k);
        ABf[m1 * 36 + k] = (_Float16)(wm.x * f0 + wm.y * f1);
        ABf[m2 * 36 + k] = (_Float16)(wm.x * g0 + wm.y * g1);
    }
    __syncthreads();
    {
        const int kk = t >> 5, hh = t & 31;
        const float2 wk2 = *reinterpret_cast<const float2*>(w1k + 2 * hh);
        ABf[(64 + kk) * 36 + hh] = (_Float16)(wk2.x * MSGf[2 * kk] + wk2.y * MSGf[2 * kk + 1]);
    }
    __syncthreads();
#pragma unroll 1
    for (int half = 0; half < 2; ++half) {
        const int n = half ? (t + 1024) : t;
        const int m = half ? m2 : m1;
        const float xa = half ? a2.x : a1.x;
        const float xb = half ? a2.y : a1.y;
#define DECL_ACC(h) float acc##h = (float)ABf[m * 36 + h] + (float)ABf[(64 + k) * 36 + h] \
                                 + w1s[h * 2] * xa + w1s[h * 2 + 1] * xb;
        RPT32(DECL_ACC)
#undef DECL_ACC
#define ST(p, h0, h1) Xh[n * 18 + p] = pk(fmaxf(acc##h0, 0.f) * LAYER_SCALE, \
                                          fmaxf(acc##h1, 0.f) * LAYER_SCALE);
        RPT16P(ST)
#undef ST
    }
    __syncthreads();

    // ================= layers 2-4 (MFMA path) =================
    phase_msg(Xh, MSG, t); __syncthreads();
    phase_small(w2m, w2k, MSG, ABu, t); __syncthreads();
    phase_main(w2s, Xh, ABu, t); __syncthreads();

    phase_msg(Xh, MSG, t); __syncthreads();
    phase_small(w3m, w3k, MSG, ABu, t); __syncthreads();
    phase_main(w3s, Xh, ABu, t); __syncthreads();

    phase_msg(Xh, MSG, t); __syncthreads();
    phase_small(w4m, w4k, MSG, ABu, t); __syncthreads();
    phase_main(w4s, Xh, ABu, t); __syncthreads();

    // ================= layer 5 (d_out=2, scalar) =================
    phase_msg(Xh, MSG, t); __syncthreads();
    if (t < 128) {                       // A5[m][h] = Wm5[h,:].msg_m[m]
        const int m = t & 63, h = t >> 6;
        float acc = 0.f;
#pragma unroll
        for (int p = 0; p < 16; ++p) {
            const float2 u = upk(MSG[m * 18 + p]);
            acc += w5m[h * 32 + 2 * p] * u.x + w5m[h * 32 + 2 * p + 1] * u.y;
        }
        ABf[m * 36 + h] = (_Float16)acc;
    } else if (t < 192) {                // B5[k][h] = Wk5[h,:].msg_k[k]
        const int idx = t - 128;
        const int kk = idx & 31, h = idx >> 5;
        float acc = 0.f;
#pragma unroll
        for (int p = 0; p < 16; ++p) {
            const float2 u = upk(MSG[(64 + kk) * 18 + p]);
            acc += w5k[h * 32 + 2 * p] * u.x + w5k[h * 32 + 2 * p + 1] * u.y;
        }
        ABf[(64 + kk) * 36 + h] = (_Float16)acc;
    }
    __syncthreads();

    float za0 = (float)ABf[m1 * 36 + 0] + (float)ABf[(64 + k) * 36 + 0];
    float za1 = (float)ABf[m1 * 36 + 1] + (float)ABf[(64 + k) * 36 + 1];
    float zb0 = (float)ABf[m2 * 36 + 0] + (float)ABf[(64 + k) * 36 + 0];
    float zb1 = (float)ABf[m2 * 36 + 1] + (float)ABf[(64 + k) * 36 + 1];
#pragma unroll
    for (int p = 0; p < 16; ++p) {
        const float2 u = upk(Xh[t * 18 + p]);
        za0 += w5s[2 * p] * u.x + w5s[2 * p + 1] * u.y;
        za1 += w5s[32 + 2 * p] * u.x + w5s[32 + 2 * p + 1] * u.y;
        const float2 v = upk(Xh[(t + 1024) * 18 + p]);
        zb0 += w5s[2 * p] * v.x + w5s[2 * p + 1] * v.y;
        zb1 += w5s[32 + 2 * p] * v.x + w5s[32 + 2 * p + 1] * v.y;
    }

    // ---- pwr_norm (scale-invariant: all per-item multipliers cancel) ----
    float p2 = za0 * za0 + za1 * za1 + zb0 * zb0 + zb1 * zb1;
#pragma unroll
    for (int mask = 1; mask <= 32; mask <<= 1) p2 += __shfl_xor(p2, mask);
    if (lane == 0) red[wave] = p2;
    __syncthreads();
    if (t == 0) {
        float tot = 0.f;
#pragma unroll
        for (int i = 0; i < 16; ++i) tot += red[i];
        red[16] = rsqrtf(tot);
    }
    __syncthreads();
    const float alpha = red[16];

    float2 r1, r2;
    r1.x = alpha * za0; r1.y = alpha * za1;
    r2.x = alpha * zb0; r2.y = alpha * zb1;
    *reinterpret_cast<float2*>(out + (size_t)b * 4096 + 2 * t) = r1;
    *reinterpret_cast<float2*>(out + (size_t)b * 4096 + 2048 + 2 * t) = r2;
}

}  // namespace

extern "C" void kernel_launch(void* const* d_in, const int* in_sizes, int n_in,
                              void* d_out, int out_size, void* d_ws, size_t ws_size,
                              hipStream_t stream) {
    const float* xg  = (const float*)d_in[0];
    const float* w1s = (const float*)d_in[1];
    const float* w1m = (const float*)d_in[2];
    const float* w1k = (const float*)d_in[3];
    const float* w2s = (const float*)d_in[4];
    const float* w2m = (const float*)d_in[5];
    const float* w2k = (const float*)d_in[6];
    const float* w3s = (const float*)d_in[7];
    const float* w3m = (const float*)d_in[8];
    const float* w3k = (const float*)d_in[9];
    const float* w4s = (const float*)d_in[10];
    const float* w4m = (const float*)d_in[11];
    const float* w4k = (const float*)d_in[12];
    const float* w5s = (const float*)d_in[13];
    const float* w5m = (const float*)d_in[14];
    const float* w5k = (const float*)d_in[15];
    float* out = (float*)d_out;

    hipLaunchKernelGGL(gnn_fused, dim3(1024), dim3(NTHREADS), 0, stream,
                       xg, w1s, w1m, w1k, w2s, w2m, w2k, w3s, w3m, w3k,
                       w4s, w4m, w4k, w5s, w5m, w5k, out);
}

// Round 12
// 221.915 us; speedup vs baseline: 10.6775x; 1.0678x over previous
//
#include <hip/hip_runtime.h>
#include <hip/hip_fp16.h>

// Precoding GNN: 5 layers of z = Ws*x + Wm*(sum_k x) + Wk*(sum_m x), ReLU(1-4),
// then Frobenius power normalization per batch item.
// M=64 antennas, K=32 users, D=32 hidden, BS=1024.
//
// One 1024-thread block per batch item. All node state in LDS as fp16,
// row-major Xh[node][32 feats], row stride 18 dwords.
//
// R11 (passed, 160us/dispatch): LDS-pipe-bound -- ~224 LDS instrs/thread/layer
//   (strided b32 msg reads, 80 scalar b16 AB reads, 64 scalar b16 D writes),
//   8.6M bank-conflict cycles. MFMA nearly free (3.4%).
// R12: flip MFMA orientation: D = Ws_tile x X^T (A-frag = Ws rows, B-frag =
//   X rows; both use the same lane layout, so the load helpers are reused).
//   Lane now holds 4 consecutive h's of one node -> D store = 1 ds_write_b64
//   per tile (was 8 b16); acc-init = 4 b64 reads (A-part wave-broadcast);
//   msg phase reads b64 with a 3m bank rotation (max 2-way aliasing = free).
//   ~3x fewer LDS instructions per layer.
// Numerics (R7-R10 lessons): LAYER_SCALE 2^-7 per stored activation
//   compensates the ~64x aggregation gain; bias-free positively-homogeneous
//   net + scale-invariant pwr_norm => output unchanged; overflow impossible.

namespace {

constexpr int NTHREADS = 1024;
constexpr float INPUT_SCALE = 0.0625f;      // 2^-4 exact
constexpr float LAYER_SCALE = 0.0078125f;   // 2^-7 exact, applied at each act store

typedef _Float16 half8 __attribute__((ext_vector_type(8)));
typedef float    f32x4 __attribute__((ext_vector_type(4)));
typedef unsigned uint4v __attribute__((ext_vector_type(4)));

#define RPT32(X) X(0)X(1)X(2)X(3)X(4)X(5)X(6)X(7)X(8)X(9)X(10)X(11)X(12)X(13)X(14)X(15) \
                 X(16)X(17)X(18)X(19)X(20)X(21)X(22)X(23)X(24)X(25)X(26)X(27)X(28)X(29)X(30)X(31)
#define RPT16P(X) X(0,0,1)X(1,2,3)X(2,4,5)X(3,6,7)X(4,8,9)X(5,10,11)X(6,12,13)X(7,14,15) \
                  X(8,16,17)X(9,18,19)X(10,20,21)X(11,22,23)X(12,24,25)X(13,26,27)X(14,28,29)X(15,30,31)

__device__ __forceinline__ unsigned pk(float a, float b) {
    __half2 h = __floats2half2_rn(a, b);
    return *reinterpret_cast<unsigned*>(&h);
}
__device__ __forceinline__ float2 upk(unsigned w) {
    __half2 h;
    *reinterpret_cast<unsigned*>(&h) = w;
    return __half22float2(h);
}

// Frag loader from an 18-dword-stride fp16x2 LDS matrix: lane gets
// row's halves [quad*8 .. quad*8+7]. Serves as A-frag (row = lane&15 = m)
// or B-frag (column = lane&15 = n) -- same register layout.
__device__ __forceinline__ half8 load_xfrag(const unsigned* base18, int row, int quad) {
    const unsigned* ap = base18 + row * 18 + quad * 4;
    const uint2 p0 = *reinterpret_cast<const uint2*>(ap);
    const uint2 p1 = *reinterpret_cast<const uint2*>(ap + 2);
    uint4v raw;
    raw.x = p0.x; raw.y = p0.y; raw.z = p1.x; raw.w = p1.y;
    return __builtin_bit_cast(half8, raw);
}

// Frag from weight W (d_out x 32 fp32, row-major): lane gets W[h][quad*8+j].
// As A-operand (h = lane&15): D = W x B.  As B-operand: D = A x W^T.
__device__ __forceinline__ half8 load_wfrag(const float* __restrict__ W, int h, int quad) {
    const float4* wr = reinterpret_cast<const float4*>(W + h * 32 + quad * 8);
    const float4 w0 = wr[0];
    const float4 w1 = wr[1];
    half8 b;
    b[0] = (_Float16)w0.x; b[1] = (_Float16)w0.y; b[2] = (_Float16)w0.z; b[3] = (_Float16)w0.w;
    b[4] = (_Float16)w1.x; b[5] = (_Float16)w1.y; b[6] = (_Float16)w1.z; b[7] = (_Float16)w1.w;
    return b;
}

// ---- phase A: msg_m[64][32] (rows 0-63) and msg_k[32][32] (rows 64-95) ----
// b64 reads. waves 8-15: msg_m (1 item = (m, fp2), 32 reads); waves 0-3:
// msg_k (1 item = (k, fp2), 64 reads); waves 4-7 idle (pipe-bound anyway).
__device__ __forceinline__ void phase_msg(const unsigned* __restrict__ Xh,
                                          unsigned* __restrict__ MSG, int t) {
    if (t >= 512) {
        const int item = t - 512;
        const int fp2 = item & 7, m = item >> 3;
        float s0 = 0.f, s1 = 0.f, s2 = 0.f, s3 = 0.f;
#pragma unroll 8
        for (int kk = 0; kk < 32; ++kk) {
            const int k = (kk + 3 * m) & 31;   // rotation: max 2-way bank aliasing
            const uint2 u = *reinterpret_cast<const uint2*>(Xh + (m * 32 + k) * 18 + fp2 * 2);
            const float2 p = upk(u.x), q = upk(u.y);
            s0 += p.x; s1 += p.y; s2 += q.x; s3 += q.y;
        }
        uint2 r; r.x = pk(s0, s1); r.y = pk(s2, s3);
        *reinterpret_cast<uint2*>(MSG + m * 18 + fp2 * 2) = r;
    } else if (t < 256) {
        const int k = t >> 3, fp2 = t & 7;
        float s0 = 0.f, s1 = 0.f, s2 = 0.f, s3 = 0.f;
#pragma unroll 8
        for (int mm = 0; mm < 64; ++mm) {
            const uint2 u = *reinterpret_cast<const uint2*>(Xh + (mm * 32 + k) * 18 + fp2 * 2);
            const float2 p = upk(u.x), q = upk(u.y);
            s0 += p.x; s1 += p.y; s2 += q.x; s3 += q.y;
        }
        uint2 r; r.x = pk(s0, s1); r.y = pk(s2, s3);
        *reinterpret_cast<uint2*>(MSG + (64 + k) * 18 + fp2 * 2) = r;
    }
}

// ---- phase B: A[64][32] = msg_m*Wm^T (waves 0-7), B[32][32] = msg_k*Wk^T
//      (waves 8-11), 1 MFMA each; D stored fp16 into AB rows 0-63 / 64-95 ----
__device__ __forceinline__ void phase_small(const float* __restrict__ Wmg,
                                            const float* __restrict__ Wkg,
                                            const unsigned* __restrict__ MSG,
                                            unsigned* __restrict__ ABu, int t) {
    const int w = t >> 6, lane = t & 63;
    if (w < 12) {
        const int isb = (w >= 8);
        const int ww = isb ? (w - 8) : w;
        const int mt = ww >> 1, nt = ww & 1;
        const int rowbase = (isb ? 64 : 0) + mt * 16;
        const int quad = lane >> 4, col = lane & 15;
        const half8 a = load_xfrag(MSG, rowbase + col, quad);   // A[row=col][k]
        const int h = nt * 16 + col;
        const half8 b = load_wfrag(isb ? Wkg : Wmg, h, quad);   // B[k][n=h]
        f32x4 c = {0.f, 0.f, 0.f, 0.f};
        c = __builtin_amdgcn_mfma_f32_16x16x32_f16(a, b, c, 0, 0, 0);
        _Float16* ABf = reinterpret_cast<_Float16*>(ABu);
        const int r0 = rowbase + quad * 4;
        ABf[(r0 + 0) * 36 + h] = (_Float16)c[0];
        ABf[(r0 + 1) * 36 + h] = (_Float16)c[1];
        ABf[(r0 + 2) * 36 + h] = (_Float16)c[2];
        ABf[(r0 + 3) * 36 + h] = (_Float16)c[3];
    }
}

// ---- phase C (flipped): D = Ws_tile x X_group^T.  Lane (quad,col) holds
//      D[h=quad*4+reg][node=node0+col] -> packed b64 store, b64 acc-init.
__device__ __forceinline__ void phase_main(const float* __restrict__ Wsg,
                                           unsigned* __restrict__ Xh,
                                           const unsigned* __restrict__ ABu, int t) {
    const int w = t >> 6, lane = t & 63;
    const int quad = lane >> 4, col = lane & 15;
    const half8 a0 = load_wfrag(Wsg, col, quad);        // A: Ws rows h=col
    const half8 a1 = load_wfrag(Wsg, 16 + col, quad);   // A: Ws rows h=col+16
    const uint2* AB2 = reinterpret_cast<const uint2*>(ABu);  // row stride 9 uint2
#pragma unroll 2
    for (int i = 0; i < 8; ++i) {
        const int T = w + i * 16;          // node group: rows T*16..T*16+15
        const int node0 = T * 16;
        const int m = T >> 1;              // whole group shares antenna m
        const int k0 = (T & 1) * 16;       // lane's user k = k0 + col
        const half8 b = load_xfrag(Xh, node0 + col, quad);  // B[k=d][n=node]
        const int krow = 64 + k0 + col;
        const uint2 Am0 = AB2[m * 9 + quad];        // A[m][quad*4..+3] (broadcast)
        const uint2 Am1 = AB2[m * 9 + 4 + quad];    // A[m][16+quad*4..+3]
        const uint2 Bk0 = AB2[krow * 9 + quad];     // B[k][quad*4..+3]
        const uint2 Bk1 = AB2[krow * 9 + 4 + quad];
        const float2 a0p = upk(Am0.x), a0q = upk(Am0.y);
        const float2 a1p = upk(Am1.x), a1q = upk(Am1.y);
        const float2 b0p = upk(Bk0.x), b0q = upk(Bk0.y);
        const float2 b1p = upk(Bk1.x), b1q = upk(Bk1.y);
        f32x4 c0, c1;
        c0[0] = a0p.x + b0p.x; c0[1] = a0p.y + b0p.y;
        c0[2] = a0q.x + b0q.x; c0[3] = a0q.y + b0q.y;
        c1[0] = a1p.x + b1p.x; c1[1] = a1p.y + b1p.y;
        c1[2] = a1q.x + b1q.x; c1[3] = a1q.y + b1q.y;
        c0 = __builtin_amdgcn_mfma_f32_16x16x32_f16(a0, b, c0, 0, 0, 0);
        c1 = __builtin_amdgcn_mfma_f32_16x16x32_f16(a1, b, c1, 0, 0, 0);
        uint2 w0, w1;
        w0.x = pk(fmaxf(c0[0], 0.f) * LAYER_SCALE, fmaxf(c0[1], 0.f) * LAYER_SCALE);
        w0.y = pk(fmaxf(c0[2], 0.f) * LAYER_SCALE, fmaxf(c0[3], 0.f) * LAYER_SCALE);
        w1.x = pk(fmaxf(c1[0], 0.f) * LAYER_SCALE, fmaxf(c1[1], 0.f) * LAYER_SCALE);
        w1.y = pk(fmaxf(c1[2], 0.f) * LAYER_SCALE, fmaxf(c1[3], 0.f) * LAYER_SCALE);
        unsigned* dst = Xh + (node0 + col) * 18 + quad * 2;
        *reinterpret_cast<uint2*>(dst) = w0;       // h quad*4..+3
        *reinterpret_cast<uint2*>(dst + 8) = w1;   // h 16+quad*4..+3
    }
}

__global__ void __launch_bounds__(NTHREADS) gnn_fused(
    const float* __restrict__ xg,
    const float* __restrict__ w1s, const float* __restrict__ w1m, const float* __restrict__ w1k,
    const float* __restrict__ w2s, const float* __restrict__ w2m, const float* __restrict__ w2k,
    const float* __restrict__ w3s, const float* __restrict__ w3m, const float* __restrict__ w3k,
    const float* __restrict__ w4s, const float* __restrict__ w4m, const float* __restrict__ w4k,
    const float* __restrict__ w5s, const float* __restrict__ w5m, const float* __restrict__ w5k,
    float* __restrict__ out)
{
    __shared__ __align__(16) unsigned Xh[2048 * 18];   // node state fp16x2, 144 KiB
    __shared__ __align__(16) unsigned MSG[96 * 18];    // msg_m | msg_k, fp16x2
    __shared__ __align__(16) unsigned ABu[96 * 18];    // A | B, fp16 (halves, stride 36)
    __shared__ float red[17];

    const int t = threadIdx.x;
    const int b = blockIdx.x;
    const int k = t & 31;
    const int m1 = t >> 5;
    const int m2 = m1 + 32;
    const int lane = t & 63;
    const int wave = t >> 6;

    float2 a1 = *reinterpret_cast<const float2*>(xg + (size_t)b * 4096 + 2 * t);
    float2 a2 = *reinterpret_cast<const float2*>(xg + (size_t)b * 4096 + 2048 + 2 * t);
    a1.x *= INPUT_SCALE; a1.y *= INPUT_SCALE;
    a2.x *= INPUT_SCALE; a2.y *= INPUT_SCALE;

    _Float16* ABf = reinterpret_cast<_Float16*>(ABu);
    float* MSGf = reinterpret_cast<float*>(MSG);

    // ================= layer 1 (d_in=2, scalar path) =================
    if (t < 64) MSGf[t] = 0.f;
    __syncthreads();
    {
        float s0 = a1.x + a2.x, s1 = a1.y + a2.y;
        s0 += __shfl_xor(s0, 32);
        s1 += __shfl_xor(s1, 32);
        if (lane < 32) {
            atomicAdd(&MSGf[2 * k], s0);
            atomicAdd(&MSGf[2 * k + 1], s1);
        }
        float f0 = a1.x, f1 = a1.y, g0 = a2.x, g1 = a2.y;
#pragma unroll
        for (int mask = 1; mask <= 16; mask <<= 1) {
            f0 += __shfl_xor(f0, mask); f1 += __shfl_xor(f1, mask);
            g0 += __shfl_xor(g0, mask); g1 += __shfl_xor(g1, mask);
        }
        const float2 wm = *reinterpret_cast<const float2*>(w1m + 2 * k);
        ABf[m1 * 36 + k] = (_Float16)(wm.x * f0 + wm.y * f1);
        ABf[m2 * 36 + k] = (_Float16)(wm.x * g0 + wm.y * g1);
    }
    __syncthreads();
    {
        const int kk = t >> 5, hh = t & 31;
        const float2 wk2 = *reinterpret_cast<const float2*>(w1k + 2 * hh);
        ABf[(64 + kk) * 36 + hh] = (_Float16)(wk2.x * MSGf[2 * kk] + wk2.y * MSGf[2 * kk + 1]);
    }
    __syncthreads();
#pragma unroll 1
    for (int half = 0; half < 2; ++half) {
        const int n = half ? (t + 1024) : t;
        const int m = half ? m2 : m1;
        const float xa = half ? a2.x : a1.x;
        const float xb = half ? a2.y : a1.y;
#define DECL_ACC(h) float acc##h = (float)ABf[m * 36 + h] + (float)ABf[(64 + k) * 36 + h] \
                                 + w1s[h * 2] * xa + w1s[h * 2 + 1] * xb;
        RPT32(DECL_ACC)
#undef DECL_ACC
#define ST(p, h0, h1) Xh[n * 18 + p] = pk(fmaxf(acc##h0, 0.f) * LAYER_SCALE, \
                                          fmaxf(acc##h1, 0.f) * LAYER_SCALE);
        RPT16P(ST)
#undef ST
    }
    __syncthreads();

    // ================= layers 2-4 (MFMA path) =================
    phase_msg(Xh, MSG, t); __syncthreads();
    phase_small(w2m, w2k, MSG, ABu, t); __syncthreads();
    phase_main(w2s, Xh, ABu, t); __syncthreads();

    phase_msg(Xh, MSG, t); __syncthreads();
    phase_small(w3m, w3k, MSG, ABu, t); __syncthreads();
    phase_main(w3s, Xh, ABu, t); __syncthreads();

    phase_msg(Xh, MSG, t); __syncthreads();
    phase_small(w4m, w4k, MSG, ABu, t); __syncthreads();
    phase_main(w4s, Xh, ABu, t); __syncthreads();

    // ================= layer 5 (d_out=2, scalar) =================
    phase_msg(Xh, MSG, t); __syncthreads();
    if (t < 128) {                       // A5[m][h] = Wm5[h,:].msg_m[m]
        const int m = t & 63, h = t >> 6;
        float acc = 0.f;
#pragma unroll
        for (int p = 0; p < 16; ++p) {
            const float2 u = upk(MSG[m * 18 + p]);
            acc += w5m[h * 32 + 2 * p] * u.x + w5m[h * 32 + 2 * p + 1] * u.y;
        }
        ABf[m * 36 + h] = (_Float16)acc;
    } else if (t < 192) {                // B5[k][h] = Wk5[h,:].msg_k[k]
        const int idx = t - 128;
        const int kk = idx & 31, h = idx >> 5;
        float acc = 0.f;
#pragma unroll
        for (int p = 0; p < 16; ++p) {
            const float2 u = upk(MSG[(64 + kk) * 18 + p]);
            acc += w5k[h * 32 + 2 * p] * u.x + w5k[h * 32 + 2 * p + 1] * u.y;
        }
        ABf[(64 + kk) * 36 + h] = (_Float16)acc;
    }
    __syncthreads();

    float za0 = (float)ABf[m1 * 36 + 0] + (float)ABf[(64 + k) * 36 + 0];
    float za1 = (float)ABf[m1 * 36 + 1] + (float)ABf[(64 + k) * 36 + 1];
    float zb0 = (float)ABf[m2 * 36 + 0] + (float)ABf[(64 + k) * 36 + 0];
    float zb1 = (float)ABf[m2 * 36 + 1] + (float)ABf[(64 + k) * 36 + 1];
#pragma unroll
    for (int p = 0; p < 16; ++p) {
        const float2 u = upk(Xh[t * 18 + p]);
        za0 += w5s[2 * p] * u.x + w5s[2 * p + 1] * u.y;
        za1 += w5s[32 + 2 * p] * u.x + w5s[32 + 2 * p + 1] * u.y;
        const float2 v = upk(Xh[(t + 1024) * 18 + p]);
        zb0 += w5s[2 * p] * v.x + w5s[2 * p + 1] * v.y;
        zb1 += w5s[32 + 2 * p] * v.x + w5s[32 + 2 * p + 1] * v.y;
    }

    // ---- pwr_norm (scale-invariant: all per-item multipliers cancel) ----
    float p2 = za0 * za0 + za1 * za1 + zb0 * zb0 + zb1 * zb1;
#pragma unroll
    for (int mask = 1; mask <= 32; mask <<= 1) p2 += __shfl_xor(p2, mask);
    if (lane == 0) red[wave] = p2;
    __syncthreads();
    if (t == 0) {
        float tot = 0.f;
#pragma unroll
        for (int i = 0; i < 16; ++i) tot += red[i];
        red[16] = rsqrtf(tot);
    }
    __syncthreads();
    const float alpha = red[16];

    float2 r1, r2;
    r1.x = alpha * za0; r1.y = alpha * za1;
    r2.x = alpha * zb0; r2.y = alpha * zb1;
    *reinterpret_cast<float2*>(out + (size_t)b * 4096 + 2 * t) = r1;
    *reinterpret_cast<float2*>(out + (size_t)b * 4096 + 2048 + 2 * t) = r2;
}

}  // namespace

extern "C" void kernel_launch(void* const* d_in, const int* in_sizes, int n_in,
                              void* d_out, int out_size, void* d_ws, size_t ws_size,
                              hipStream_t stream) {
    const float* xg  = (const float*)d_in[0];
    const float* w1s = (const float*)d_in[1];
    const float* w1m = (const float*)d_in[2];
    const float* w1k = (const float*)d_in[3];
    const float* w2s = (const float*)d_in[4];
    const float* w2m = (const float*)d_in[5];
    const float* w2k = (const float*)d_in[6];
    const float* w3s = (const float*)d_in[7];
    const float* w3m = (const float*)d_in[8];
    const float* w3k = (const float*)d_in[9];
    const float* w4s = (const float*)d_in[10];
    const float* w4m = (const float*)d_in[11];
    const float* w4k = (const float*)d_in[12];
    const float* w5s = (const float*)d_in[13];
    const float* w5m = (const float*)d_in[14];
    const float* w5k = (const float*)d_in[15];
    float* out = (float*)d_out;

    hipLaunchKernelGGL(gnn_fused, dim3(1024), dim3(NTHREADS), 0, stream,
                       xg, w1s, w1m, w1k, w2s, w2m, w2k, w3s, w3m, w3k,
                       w4s, w4m, w4k, w5s, w5m, w5k, out);
}